// Round 1
// baseline (369.565 us; speedup 1.0000x reference)
//
#include <hip/hip_runtime.h>
#include <hip/hip_bf16.h>
#include <stdint.h>

#define B_ 4
#define S_ 2048
#define E_ 1024
#define BS_ (B_*S_)

using bf16x8 = __attribute__((ext_vector_type(8))) __bf16;
using f32x4  = __attribute__((ext_vector_type(4))) float;

__device__ __forceinline__ unsigned short f2bf(float f) {
  unsigned int u = __float_as_uint(f);
  u += 0x7fffu + ((u >> 16) & 1u);          // round-to-nearest-even
  return (unsigned short)(u >> 16);
}

// ---------------- fp32 -> bf16 convert (x4 vectorized) ----------------
__global__ __launch_bounds__(256) void conv_f32_bf16(const float* __restrict__ in,
                                                     unsigned short* __restrict__ out,
                                                     int n4) {
  int i = blockIdx.x * 256 + threadIdx.x;
  if (i >= n4) return;
  const float4 v = ((const float4*)in)[i];
  ushort4 o;
  o.x = f2bf(v.x); o.y = f2bf(v.y); o.z = f2bf(v.z); o.w = f2bf(v.w);
  ((ushort4*)out)[i] = o;
}

// ---------------- shared BT-GEMM: C[m][n] = sum_k A[m][k]*B[n][k] ----------------
// EPI 0: +bias[col] -> bf16 out
// EPI 1: *scale -> fp32 out, causal => skip blocks fully above diagonal
// EPI 2: fp32 out, causal => K-loop clipped at m0+BM (A upper part is zeros)
template<int EPI>
__global__ __launch_bounds__(256, 2) void gemm_bt(
    const unsigned short* __restrict__ A, const unsigned short* __restrict__ Bm,
    float* __restrict__ Cf, unsigned short* __restrict__ Cb,
    const float* __restrict__ bias,
    int M, int N, int K, int lda, int ldb, int ldc,
    long sA, long sB, long sC, float scale, int causal)
{
  constexpr int BM = 128, BN = 128, BK = 64, LDP = BK + 8;  // +8 bf16 pad = +16B, keeps 16B align
  __shared__ __align__(16) unsigned short As[BM][LDP];
  __shared__ __align__(16) unsigned short Bs[BN][LDP];
  const int bz = blockIdx.z;
  A  += sA * bz;
  Bm += sB * bz;
  const int m0 = blockIdx.y * BM, n0 = blockIdx.x * BN;
  if (EPI == 1 && causal && n0 >= m0 + BM) return;           // fully masked block
  const int kend = (EPI == 2 && causal) ? min(K, m0 + BM) : K;
  const int t = threadIdx.x;
  const int lane = t & 63, wave = t >> 6;
  const int wr = wave >> 1, wc = wave & 1;
  const int q = lane >> 4, r = lane & 15;
  f32x4 acc[4][4] = {};

  for (int k0 = 0; k0 < kend; k0 += BK) {
    __syncthreads();
#pragma unroll
    for (int c = 0; c < 4; ++c) {
      const int chunk = t + 256 * c;          // 1024 chunks of 8 bf16 (16B)
      const int row = chunk >> 3;             // 8 chunks per 64-wide row
      const int col = (chunk & 7) << 3;
      *(bf16x8*)&As[row][col] = *(const bf16x8*)&A[(long)(m0 + row) * lda + k0 + col];
      *(bf16x8*)&Bs[row][col] = *(const bf16x8*)&Bm[(long)(n0 + row) * ldb + k0 + col];
    }
    __syncthreads();
#pragma unroll
    for (int kk = 0; kk < BK; kk += 32) {
      bf16x8 af[4], bfr[4];
#pragma unroll
      for (int i = 0; i < 4; ++i)
        af[i] = *(const bf16x8*)&As[wr * 64 + i * 16 + r][kk + q * 8];
#pragma unroll
      for (int j = 0; j < 4; ++j)
        bfr[j] = *(const bf16x8*)&Bs[wc * 64 + j * 16 + r][kk + q * 8];
#pragma unroll
      for (int i = 0; i < 4; ++i)
#pragma unroll
        for (int j = 0; j < 4; ++j)
          acc[i][j] = __builtin_amdgcn_mfma_f32_16x16x32_bf16(af[i], bfr[j], acc[i][j], 0, 0, 0);
    }
  }

  if (EPI == 0) Cb += sC * bz; else Cf += sC * bz;
#pragma unroll
  for (int i = 0; i < 4; ++i) {
#pragma unroll
    for (int j = 0; j < 4; ++j) {
      const int col = n0 + wc * 64 + j * 16 + r;      // C/D: col = lane&15
#pragma unroll
      for (int e = 0; e < 4; ++e) {
        const int rowg = m0 + wr * 64 + i * 16 + q * 4 + e;  // row = quad*4 + reg
        float v = acc[i][j][e];
        if (EPI == 0) {
          v += bias[col];
          Cb[(long)rowg * ldc + col] = f2bf(v);
        } else if (EPI == 1) {
          Cf[(long)rowg * ldc + col] = v * scale;
        } else {
          Cf[(long)rowg * ldc + col] = v;
        }
      }
    }
  }
}

// ---------------- bf16 transpose per batch: V[S][E] -> Vt[E][S] ----------------
__global__ __launch_bounds__(256) void transpose_b(const unsigned short* __restrict__ V,
                                                   unsigned short* __restrict__ Vt) {
  __shared__ unsigned short tile[32][33];
  const int b = blockIdx.z;
  const unsigned short* Vb = V + (long)b * S_ * E_;
  unsigned short* Vtb = Vt + (long)b * S_ * E_;
  const int e0 = blockIdx.x * 32, j0 = blockIdx.y * 32;
  const int tx = threadIdx.x, ty = threadIdx.y;   // 32 x 8
#pragma unroll
  for (int i = 0; i < 32; i += 8)
    tile[ty + i][tx] = Vb[(long)(j0 + ty + i) * E_ + e0 + tx];
  __syncthreads();
#pragma unroll
  for (int i = 0; i < 32; i += 8)
    Vtb[(long)(e0 + ty + i) * S_ + j0 + tx] = tile[tx][ty + i];
}

// ---------------- causal softmax, P written bf16 in-place over the fp32 scores row ----------------
__global__ __launch_bounds__(256) void softmax_causal(float* __restrict__ Sc) {
  __shared__ float ex[S_];
  __shared__ float rmax[4], rsum[4];
  const int row = blockIdx.x;                 // 0..B*S-1
  const int b = row >> 11, ii = row & (S_ - 1);
  float* srow = Sc + (long)b * S_ * S_ + (long)ii * S_;
  unsigned short* prow = (unsigned short*)srow;   // bf16 row, stride 2*S_ elems between rows
  const int len = ii + 1;
  const int t = threadIdx.x;
  const int lane = t & 63, wave = t >> 6;
  float mx = -3.0e38f;
  for (int j = t; j < len; j += 256) { float s = srow[j]; ex[j] = s; mx = fmaxf(mx, s); }
#pragma unroll
  for (int o = 32; o; o >>= 1) mx = fmaxf(mx, __shfl_xor(mx, o));
  if (lane == 0) rmax[wave] = mx;
  __syncthreads();
  mx = fmaxf(fmaxf(rmax[0], rmax[1]), fmaxf(rmax[2], rmax[3]));
  float sum = 0.f;
  for (int j = t; j < len; j += 256) { float e = __expf(ex[j] - mx); ex[j] = e; sum += e; }
#pragma unroll
  for (int o = 32; o; o >>= 1) sum += __shfl_xor(sum, o);
  if (lane == 0) rsum[wave] = sum;
  __syncthreads();                              // also guarantees all srow reads are done
  sum = rsum[0] + rsum[1] + rsum[2] + rsum[3];
  const float inv = 1.0f / sum;
  for (int j = t; j < S_; j += 256)
    prow[j] = (j < len) ? f2bf(ex[j] * inv) : (unsigned short)0;
}

// ---------------- residual + LayerNorm ----------------
__global__ __launch_bounds__(256) void residual_ln(
    const float* __restrict__ attn, const float* __restrict__ x,
    const float* __restrict__ gamma, const float* __restrict__ beta,
    float* __restrict__ out) {
  __shared__ float rs[4], rs2[4];
  const long row = blockIdx.x;
  const int t = threadIdx.x;
  const int lane = t & 63, wave = t >> 6;
  const float4 a  = ((const float4*)(attn + row * E_))[t];
  const float4 xv = ((const float4*)(x + row * E_))[t];
  const float y0 = a.x + xv.x, y1 = a.y + xv.y, y2 = a.z + xv.z, y3 = a.w + xv.w;
  float s  = y0 + y1 + y2 + y3;
  float s2 = y0 * y0 + y1 * y1 + y2 * y2 + y3 * y3;
#pragma unroll
  for (int o = 32; o; o >>= 1) { s += __shfl_xor(s, o); s2 += __shfl_xor(s2, o); }
  if (lane == 0) { rs[wave] = s; rs2[wave] = s2; }
  __syncthreads();
  s  = rs[0] + rs[1] + rs[2] + rs[3];
  s2 = rs2[0] + rs2[1] + rs2[2] + rs2[3];
  const float mu  = s * (1.0f / E_);
  const float var = s2 * (1.0f / E_) - mu * mu;
  const float inv = rsqrtf(var + 1e-5f);
  const float4 g  = ((const float4*)gamma)[t];
  const float4 be = ((const float4*)beta)[t];
  float4 o;
  o.x = (y0 - mu) * inv * g.x + be.x;
  o.y = (y1 - mu) * inv * g.y + be.y;
  o.z = (y2 - mu) * inv * g.z + be.z;
  o.w = (y3 - mu) * inv * g.w + be.w;
  ((float4*)(out + row * E_))[t] = o;
}

extern "C" void kernel_launch(void* const* d_in, const int* in_sizes, int n_in,
                              void* d_out, int out_size, void* d_ws, size_t ws_size,
                              hipStream_t stream) {
  const float* x  = (const float*)d_in[0];
  // d_in[1] = causal mask (bool) — structurally known, not read
  const float* Wq = (const float*)d_in[2];
  const float* bq = (const float*)d_in[3];
  const float* Wk = (const float*)d_in[4];
  const float* bk = (const float*)d_in[5];
  const float* Wv = (const float*)d_in[6];
  const float* bv = (const float*)d_in[7];
  const float* gamma = (const float*)d_in[8];
  const float* beta  = (const float*)d_in[9];
  float* out = (float*)d_out;

  char* ws = (char*)d_ws;
  size_t off = 0;
  auto alloc = [&](size_t bytes) { char* p = ws + off; off += (bytes + 255) & ~(size_t)255; return p; };
  unsigned short* xb  = (unsigned short*)alloc((size_t)BS_ * E_ * 2);  // 16 MB
  unsigned short* Wqb = (unsigned short*)alloc((size_t)E_ * E_ * 2);   // 2 MB
  unsigned short* Wkb = (unsigned short*)alloc((size_t)E_ * E_ * 2);
  unsigned short* Wvb = (unsigned short*)alloc((size_t)E_ * E_ * 2);
  unsigned short* Qb  = (unsigned short*)alloc((size_t)BS_ * E_ * 2);  // 16 MB
  unsigned short* Kb  = (unsigned short*)alloc((size_t)BS_ * E_ * 2);  // 16 MB (contiguous after Qb)
  unsigned short* Vb  = (unsigned short*)alloc((size_t)BS_ * E_ * 2);
  unsigned short* Vt  = (unsigned short*)alloc((size_t)BS_ * E_ * 2);
  float* Sc = (float*)alloc((size_t)B_ * S_ * S_ * 4);                 // 64 MB; P aliases it (bf16 in-place)
  float* attn = (float*)Qb;  // 32 MB: reuse Q+K region (dead after scores GEMM)

  // 1) converts
  conv_f32_bf16<<<dim3(BS_ * E_ / 4 / 256), 256, 0, stream>>>(x, xb, BS_ * E_ / 4);
  conv_f32_bf16<<<dim3(E_ * E_ / 4 / 256), 256, 0, stream>>>(Wq, Wqb, E_ * E_ / 4);
  conv_f32_bf16<<<dim3(E_ * E_ / 4 / 256), 256, 0, stream>>>(Wk, Wkb, E_ * E_ / 4);
  conv_f32_bf16<<<dim3(E_ * E_ / 4 / 256), 256, 0, stream>>>(Wv, Wvb, E_ * E_ / 4);

  // 2) QKV projections: C[8192,1024] = xb · W^T + b  -> bf16
  dim3 g1(E_ / 128, BS_ / 128, 1);
  gemm_bt<0><<<g1, 256, 0, stream>>>(xb, Wqb, nullptr, Qb, bq, BS_, E_, E_, E_, E_, E_, 0, 0, 0, 1.f, 0);
  gemm_bt<0><<<g1, 256, 0, stream>>>(xb, Wkb, nullptr, Kb, bk, BS_, E_, E_, E_, E_, E_, 0, 0, 0, 1.f, 0);
  gemm_bt<0><<<g1, 256, 0, stream>>>(xb, Wvb, nullptr, Vb, bv, BS_, E_, E_, E_, E_, E_, 0, 0, 0, 1.f, 0);

  // 3) transpose V -> Vt per batch
  transpose_b<<<dim3(E_ / 32, S_ / 32, B_), dim3(32, 8), 0, stream>>>(Vb, Vt);

  // 4) scores = Q·K^T / 32 (causal: skip fully-masked blocks)
  dim3 g2(S_ / 128, S_ / 128, B_);
  gemm_bt<1><<<g2, 256, 0, stream>>>(Qb, Kb, Sc, nullptr, nullptr, S_, S_, E_, E_, E_, S_,
                                     (long)S_ * E_, (long)S_ * E_, (long)S_ * S_, 0.03125f, 1);

  // 5) causal softmax -> P (bf16, in-place over Sc, row stride 2*S_ bf16)
  softmax_causal<<<dim3(BS_), 256, 0, stream>>>(Sc);

  // 6) attn = P · V  (as P · Vt^T), K-loop clipped at diagonal
  dim3 g3(E_ / 128, S_ / 128, B_);
  gemm_bt<2><<<g3, 256, 0, stream>>>((const unsigned short*)Sc, Vt, attn, nullptr, nullptr,
                                     S_, E_, S_, 2 * S_, S_, E_,
                                     (long)2 * S_ * S_, (long)S_ * E_, (long)S_ * E_, 1.f, 1);

  // 7) out = LayerNorm(attn + x) * gamma + beta
  residual_ln<<<dim3(BS_), 256, 0, stream>>>(attn, x, gamma, beta, out);
}

// Round 2
// 320.016 us; speedup vs baseline: 1.1548x; 1.1548x over previous
//
#include <hip/hip_runtime.h>
#include <hip/hip_bf16.h>
#include <stdint.h>

#define B_ 4
#define S_ 2048
#define E_ 1024
#define BS_ (B_*S_)

using bf16x8 = __attribute__((ext_vector_type(8))) __bf16;
using f32x4  = __attribute__((ext_vector_type(4))) float;

__device__ __forceinline__ unsigned short f2bf(float f) {
  unsigned int u = __float_as_uint(f);
  u += 0x7fffu + ((u >> 16) & 1u);          // round-to-nearest-even
  return (unsigned short)(u >> 16);
}

// async global->LDS, 16B per lane; LDS dest = wave-uniform base + lane*16
__device__ __forceinline__ void gld16(const unsigned short* g, unsigned short* l) {
  __builtin_amdgcn_global_load_lds((__attribute__((address_space(1))) void*)(void*)g,
                                   (__attribute__((address_space(3))) void*)l, 16, 0, 0);
}

// ---------------- fp32 -> bf16 convert (x4 vectorized) ----------------
__global__ __launch_bounds__(256) void conv_f32_bf16(const float* __restrict__ in,
                                                     unsigned short* __restrict__ out,
                                                     int n4) {
  int i = blockIdx.x * 256 + threadIdx.x;
  if (i >= n4) return;
  const float4 v = ((const float4*)in)[i];
  ushort4 o;
  o.x = f2bf(v.x); o.y = f2bf(v.y); o.z = f2bf(v.z); o.w = f2bf(v.w);
  ((ushort4*)out)[i] = o;
}

__global__ __launch_bounds__(256) void concat_bias(const float* __restrict__ a,
                                                   const float* __restrict__ b,
                                                   const float* __restrict__ c,
                                                   float* __restrict__ o) {
  int i = blockIdx.x * 256 + threadIdx.x;
  if (i >= 3 * E_) return;
  o[i] = (i < E_) ? a[i] : (i < 2 * E_ ? b[i - E_] : c[i - 2 * E_]);
}

// ---------------- BT-GEMM with global_load_lds staging + XOR-swizzled LDS ----------------
// C[m][n] = sum_k A[m][k]*B[n][k]
// LDS tile: 128 rows x 64 cols bf16, stored in 16B chunks; chunk c of row r lives at
// 16B-unit r*8 + (c ^ (r&7)).  Staging picks global chunk (lane&7)^(lane>>3) so the
// hardware's base+lane*16 placement realizes exactly that layout.
// EPI 0: +bias[col] -> bf16 out
// EPI 1: *scale -> fp32 out, causal => skip blocks fully above diagonal
// EPI 2: fp32 out, causal => K-loop clipped at m0+BM (A upper part is zeros)
template<int EPI>
__global__ __launch_bounds__(256, 2) void gemm_bt(
    const unsigned short* __restrict__ A, const unsigned short* __restrict__ Bm,
    float* __restrict__ Cf, unsigned short* __restrict__ Cb,
    const float* __restrict__ bias,
    int K, int lda, int ldb, int ldc,
    long sA, long sB, long sC, float scale, int causal)
{
  constexpr int BM = 128, BN = 128, BK = 64;
  __shared__ __align__(16) unsigned short As[BM * BK];
  __shared__ __align__(16) unsigned short Bs[BN * BK];
  const int bz = blockIdx.z;
  A  += sA * bz;
  Bm += sB * bz;
  const int m0 = blockIdx.y * BM, n0 = blockIdx.x * BN;
  if (EPI == 1 && causal && n0 >= m0 + BM) return;           // fully masked block
  const int kend = (EPI == 2 && causal) ? min(K, m0 + BM) : K;
  const int t = threadIdx.x;
  const int lane = t & 63, wave = t >> 6;
  const int wr = wave >> 1, wc = wave & 1;
  const int q = lane >> 4, r = lane & 15;

  // staging: wave w handles rows [w*32, w*32+32), 4 instructions of 8 rows each
  const int srow   = lane >> 3;                 // 0..7 within an 8-row segment
  const int schunk = (lane & 7) ^ srow;         // global 16B chunk to fetch
  const long ga0 = (long)(m0 + wave * 32 + srow) * lda + schunk * 8;
  const long gb0 = (long)(n0 + wave * 32 + srow) * ldb + schunk * 8;

  f32x4 acc[4][4] = {};

  for (int k0 = 0; k0 < kend; k0 += BK) {
#pragma unroll
    for (int s = 0; s < 4; ++s) {
      gld16(A  + ga0 + (long)s * 8 * lda + k0, &As[(wave * 32 + s * 8) * 64]);
      gld16(Bm + gb0 + (long)s * 8 * ldb + k0, &Bs[(wave * 32 + s * 8) * 64]);
    }
    __syncthreads();                            // vmcnt(0) drain + barrier: tiles ready
#pragma unroll
    for (int kk = 0; kk < BK; kk += 32) {
      bf16x8 af[4], bfr[4];
      const int cq = (kk >> 3) + q;             // 16B chunk for this quad
#pragma unroll
      for (int i = 0; i < 4; ++i) {
        const int row = wr * 64 + i * 16 + r;
        af[i] = *(const bf16x8*)&As[(row * 8 + (cq ^ (r & 7))) * 8];
      }
#pragma unroll
      for (int j = 0; j < 4; ++j) {
        const int row = wc * 64 + j * 16 + r;
        bfr[j] = *(const bf16x8*)&Bs[(row * 8 + (cq ^ (r & 7))) * 8];
      }
#pragma unroll
      for (int i = 0; i < 4; ++i)
#pragma unroll
        for (int j = 0; j < 4; ++j)
          acc[i][j] = __builtin_amdgcn_mfma_f32_16x16x32_bf16(af[i], bfr[j], acc[i][j], 0, 0, 0);
    }
    __syncthreads();                            // all reads done before next staging
  }

  if (EPI == 0) Cb += sC * bz; else Cf += sC * bz;
#pragma unroll
  for (int i = 0; i < 4; ++i) {
#pragma unroll
    for (int j = 0; j < 4; ++j) {
      const int col = n0 + wc * 64 + j * 16 + r;      // C/D: col = lane&15
#pragma unroll
      for (int e = 0; e < 4; ++e) {
        const int rowg = m0 + wr * 64 + i * 16 + q * 4 + e;  // row = quad*4 + reg
        float v = acc[i][j][e];
        if (EPI == 0) {
          v += bias[col];
          Cb[(long)rowg * ldc + col] = f2bf(v);
        } else if (EPI == 1) {
          Cf[(long)rowg * ldc + col] = v * scale;
        } else {
          Cf[(long)rowg * ldc + col] = v;
        }
      }
    }
  }
}

// ---------------- bf16 transpose per batch: V[S][E] (ld lda) -> Vt[E][S] ----------------
__global__ __launch_bounds__(256) void transpose_b(const unsigned short* __restrict__ V,
                                                   unsigned short* __restrict__ Vt, int lda) {
  __shared__ unsigned short tile[32][33];
  const int b = blockIdx.z;
  const unsigned short* Vb = V + (long)b * S_ * lda;
  unsigned short* Vtb = Vt + (long)b * S_ * E_;
  const int e0 = blockIdx.x * 32, j0 = blockIdx.y * 32;
  const int tx = threadIdx.x, ty = threadIdx.y;   // 32 x 8
#pragma unroll
  for (int i = 0; i < 32; i += 8)
    tile[ty + i][tx] = Vb[(long)(j0 + ty + i) * lda + e0 + tx];
  __syncthreads();
#pragma unroll
  for (int i = 0; i < 32; i += 8)
    Vtb[(long)(e0 + ty + i) * S_ + j0 + tx] = tile[tx][ty + i];
}

// ---------------- causal softmax, P written bf16 in-place over the fp32 scores row ----------------
__global__ __launch_bounds__(256) void softmax_causal(float* __restrict__ Sc) {
  __shared__ float ex[S_];
  __shared__ float rmax[4], rsum[4];
  const int row = blockIdx.x;                 // 0..B*S-1
  const int b = row >> 11, ii = row & (S_ - 1);
  float* srow = Sc + (long)b * S_ * S_ + (long)ii * S_;
  unsigned short* prow = (unsigned short*)srow;   // bf16 row, stride 2*S_ elems between rows
  const int len = ii + 1;
  const int t = threadIdx.x;
  const int lane = t & 63, wave = t >> 6;
  float mx = -3.0e38f;
  for (int j = t; j < len; j += 256) { float s = srow[j]; ex[j] = s; mx = fmaxf(mx, s); }
#pragma unroll
  for (int o = 32; o; o >>= 1) mx = fmaxf(mx, __shfl_xor(mx, o));
  if (lane == 0) rmax[wave] = mx;
  __syncthreads();
  mx = fmaxf(fmaxf(rmax[0], rmax[1]), fmaxf(rmax[2], rmax[3]));
  float sum = 0.f;
  for (int j = t; j < len; j += 256) { float e = __expf(ex[j] - mx); ex[j] = e; sum += e; }
#pragma unroll
  for (int o = 32; o; o >>= 1) sum += __shfl_xor(sum, o);
  if (lane == 0) rsum[wave] = sum;
  __syncthreads();                              // also guarantees all srow reads are done
  sum = rsum[0] + rsum[1] + rsum[2] + rsum[3];
  const float inv = 1.0f / sum;
  for (int j = t; j < S_; j += 256)
    prow[j] = (j < len) ? f2bf(ex[j] * inv) : (unsigned short)0;
}

// ---------------- residual + LayerNorm ----------------
__global__ __launch_bounds__(256) void residual_ln(
    const float* __restrict__ attn, const float* __restrict__ x,
    const float* __restrict__ gamma, const float* __restrict__ beta,
    float* __restrict__ out) {
  __shared__ float rs[4], rs2[4];
  const long row = blockIdx.x;
  const int t = threadIdx.x;
  const int lane = t & 63, wave = t >> 6;
  const float4 a  = ((const float4*)(attn + row * E_))[t];
  const float4 xv = ((const float4*)(x + row * E_))[t];
  const float y0 = a.x + xv.x, y1 = a.y + xv.y, y2 = a.z + xv.z, y3 = a.w + xv.w;
  float s  = y0 + y1 + y2 + y3;
  float s2 = y0 * y0 + y1 * y1 + y2 * y2 + y3 * y3;
#pragma unroll
  for (int o = 32; o; o >>= 1) { s += __shfl_xor(s, o); s2 += __shfl_xor(s2, o); }
  if (lane == 0) { rs[wave] = s; rs2[wave] = s2; }
  __syncthreads();
  s  = rs[0] + rs[1] + rs[2] + rs[3];
  s2 = rs2[0] + rs2[1] + rs2[2] + rs2[3];
  const float mu  = s * (1.0f / E_);
  const float var = s2 * (1.0f / E_) - mu * mu;
  const float inv = rsqrtf(var + 1e-5f);
  const float4 g  = ((const float4*)gamma)[t];
  const float4 be = ((const float4*)beta)[t];
  float4 o;
  o.x = (y0 - mu) * inv * g.x + be.x;
  o.y = (y1 - mu) * inv * g.y + be.y;
  o.z = (y2 - mu) * inv * g.z + be.z;
  o.w = (y3 - mu) * inv * g.w + be.w;
  ((float4*)(out + row * E_))[t] = o;
}

extern "C" void kernel_launch(void* const* d_in, const int* in_sizes, int n_in,
                              void* d_out, int out_size, void* d_ws, size_t ws_size,
                              hipStream_t stream) {
  const float* x  = (const float*)d_in[0];
  // d_in[1] = causal mask (bool) — structurally known, not read
  const float* Wq = (const float*)d_in[2];
  const float* bq = (const float*)d_in[3];
  const float* Wk = (const float*)d_in[4];
  const float* bk = (const float*)d_in[5];
  const float* Wv = (const float*)d_in[6];
  const float* bv = (const float*)d_in[7];
  const float* gamma = (const float*)d_in[8];
  const float* beta  = (const float*)d_in[9];
  float* out = (float*)d_out;

  char* ws = (char*)d_ws;
  size_t off = 0;
  auto alloc = [&](size_t bytes) { char* p = ws + off; off += (bytes + 255) & ~(size_t)255; return p; };
  unsigned short* xb    = (unsigned short*)alloc((size_t)BS_ * E_ * 2);        // 16 MB
  unsigned short* Wqkvb = (unsigned short*)alloc((size_t)3 * E_ * E_ * 2);     // 6 MB
  float*          bqkv  = (float*)alloc((size_t)3 * E_ * 4);
  unsigned short* Cqkv  = (unsigned short*)alloc((size_t)BS_ * 3 * E_ * 2);    // 48 MB (Q|K|V, ld 3072)
  unsigned short* Vt    = (unsigned short*)alloc((size_t)BS_ * E_ * 2);        // 16 MB
  float*          Sc    = (float*)alloc((size_t)B_ * S_ * S_ * 4);             // 64 MB; P aliases (bf16)
  float* attn = (float*)Cqkv;   // Q/K/V dead after scores GEMM + transpose

  // 1) converts: x and concatenated W/bias
  conv_f32_bf16<<<dim3(BS_ * E_ / 4 / 256), 256, 0, stream>>>(x, xb, BS_ * E_ / 4);
  conv_f32_bf16<<<dim3(E_ * E_ / 4 / 256), 256, 0, stream>>>(Wq, Wqkvb, E_ * E_ / 4);
  conv_f32_bf16<<<dim3(E_ * E_ / 4 / 256), 256, 0, stream>>>(Wk, Wqkvb + E_ * E_, E_ * E_ / 4);
  conv_f32_bf16<<<dim3(E_ * E_ / 4 / 256), 256, 0, stream>>>(Wv, Wqkvb + 2 * E_ * E_, E_ * E_ / 4);
  concat_bias<<<dim3((3 * E_ + 255) / 256), 256, 0, stream>>>(bq, bk, bv, bqkv);

  // 2) fused QKV projection: Cqkv[8192,3072] = xb · Wqkv^T + bqkv -> bf16
  dim3 g1(3 * E_ / 128, BS_ / 128, 1);
  gemm_bt<0><<<g1, 256, 0, stream>>>(xb, Wqkvb, nullptr, Cqkv, bqkv,
                                     E_, E_, E_, 3 * E_, 0, 0, 0, 1.f, 0);

  // 3) transpose V (cols 2048..3071 of Cqkv) -> Vt[E][S] per batch
  transpose_b<<<dim3(E_ / 32, S_ / 32, B_), dim3(32, 8), 0, stream>>>(Cqkv + 2 * E_, Vt, 3 * E_);

  // 4) scores = Q·K^T / 32 (causal: skip fully-masked blocks)
  dim3 g2(S_ / 128, S_ / 128, B_);
  gemm_bt<1><<<g2, 256, 0, stream>>>(Cqkv, Cqkv + E_, Sc, nullptr, nullptr,
                                     E_, 3 * E_, 3 * E_, S_,
                                     (long)S_ * 3 * E_, (long)S_ * 3 * E_, (long)S_ * S_,
                                     0.03125f, 1);

  // 5) causal softmax -> P (bf16, in-place over Sc, row stride 2*S_ bf16)
  softmax_causal<<<dim3(BS_), 256, 0, stream>>>(Sc);

  // 6) attn = P · V  (as P · Vt^T), K-loop clipped at diagonal
  dim3 g3(E_ / 128, S_ / 128, B_);
  gemm_bt<2><<<g3, 256, 0, stream>>>((const unsigned short*)Sc, Vt, attn, nullptr, nullptr,
                                     S_, 2 * S_, S_, E_,
                                     (long)2 * S_ * S_, (long)S_ * E_, (long)S_ * E_, 1.f, 1);

  // 7) out = LayerNorm(attn + x) * gamma + beta
  residual_ln<<<dim3(BS_), 256, 0, stream>>>(attn, x, gamma, beta, out);
}

// Round 3
// 306.457 us; speedup vs baseline: 1.2059x; 1.0442x over previous
//
#include <hip/hip_runtime.h>
#include <hip/hip_bf16.h>
#include <stdint.h>

#define B_ 4
#define S_ 2048
#define E_ 1024
#define BS_ (B_*S_)

using bf16x8 = __attribute__((ext_vector_type(8))) __bf16;
using f32x4  = __attribute__((ext_vector_type(4))) float;

__device__ __forceinline__ unsigned short f2bf(float f) {
  unsigned int u = __float_as_uint(f);
  u += 0x7fffu + ((u >> 16) & 1u);          // round-to-nearest-even
  return (unsigned short)(u >> 16);
}
__device__ __forceinline__ float bf2f(unsigned short h) {
  return __uint_as_float(((unsigned int)h) << 16);
}

// async global->LDS, 16B per lane; LDS dest = wave-uniform base + lane*16
__device__ __forceinline__ void gld16(const unsigned short* g, unsigned short* l) {
  __builtin_amdgcn_global_load_lds((__attribute__((address_space(1))) void*)(void*)g,
                                   (__attribute__((address_space(3))) void*)l, 16, 0, 0);
}

// ---------------- fp32 -> bf16 convert (x4 vectorized) ----------------
__global__ __launch_bounds__(256) void conv_f32_bf16(const float* __restrict__ in,
                                                     unsigned short* __restrict__ out,
                                                     int n4) {
  int i = blockIdx.x * 256 + threadIdx.x;
  if (i >= n4) return;
  const float4 v = ((const float4*)in)[i];
  ushort4 o;
  o.x = f2bf(v.x); o.y = f2bf(v.y); o.z = f2bf(v.z); o.w = f2bf(v.w);
  ((ushort4*)out)[i] = o;
}

__global__ __launch_bounds__(256) void concat_bias(const float* __restrict__ a,
                                                   const float* __restrict__ b,
                                                   const float* __restrict__ c,
                                                   float* __restrict__ o) {
  int i = blockIdx.x * 256 + threadIdx.x;
  if (i >= 3 * E_) return;
  o[i] = (i < E_) ? a[i] : (i < 2 * E_ ? b[i - E_] : c[i - 2 * E_]);
}

// ---------------- BT-GEMM with global_load_lds staging + XOR-swizzled LDS ----------------
// C[m][n] = sum_k A[m][k]*B[n][k]
// EPI 0: +bias[col] -> bf16 out
// EPI 1: *scale -> bf16 out, causal => skip blocks fully above diagonal
// EPI 2: fp32 out, causal => K-loop clipped at m0+BM (A upper part is zeros)
template<int EPI>
__global__ __launch_bounds__(256, 2) void gemm_bt(
    const unsigned short* __restrict__ A, const unsigned short* __restrict__ Bm,
    float* __restrict__ Cf, unsigned short* __restrict__ Cb,
    const float* __restrict__ bias,
    int K, int lda, int ldb, int ldc,
    long sA, long sB, long sC, float scale, int causal)
{
  constexpr int BM = 128, BN = 128, BK = 64;
  __shared__ __align__(16) unsigned short As[BM * BK];
  __shared__ __align__(16) unsigned short Bs[BN * BK];
  const int bz = blockIdx.z;
  A  += sA * bz;
  Bm += sB * bz;
  const int m0 = blockIdx.y * BM, n0 = blockIdx.x * BN;
  if (EPI == 1 && causal && n0 >= m0 + BM) return;           // fully masked block
  const int kend = (EPI == 2 && causal) ? min(K, m0 + BM) : K;
  const int t = threadIdx.x;
  const int lane = t & 63, wave = t >> 6;
  const int wr = wave >> 1, wc = wave & 1;
  const int q = lane >> 4, r = lane & 15;

  // staging: wave w handles rows [w*32, w*32+32), 4 instructions of 8 rows each
  const int srow   = lane >> 3;                 // 0..7 within an 8-row segment
  const int schunk = (lane & 7) ^ srow;         // global 16B chunk to fetch
  const long ga0 = (long)(m0 + wave * 32 + srow) * lda + schunk * 8;
  const long gb0 = (long)(n0 + wave * 32 + srow) * ldb + schunk * 8;

  f32x4 acc[4][4] = {};

  for (int k0 = 0; k0 < kend; k0 += BK) {
#pragma unroll
    for (int s = 0; s < 4; ++s) {
      gld16(A  + ga0 + (long)s * 8 * lda + k0, &As[(wave * 32 + s * 8) * 64]);
      gld16(Bm + gb0 + (long)s * 8 * ldb + k0, &Bs[(wave * 32 + s * 8) * 64]);
    }
    __syncthreads();                            // vmcnt(0) drain + barrier: tiles ready
#pragma unroll
    for (int kk = 0; kk < BK; kk += 32) {
      bf16x8 af[4], bfr[4];
      const int cq = (kk >> 3) + q;             // 16B chunk for this quad
#pragma unroll
      for (int i = 0; i < 4; ++i) {
        const int row = wr * 64 + i * 16 + r;
        af[i] = *(const bf16x8*)&As[(row * 8 + (cq ^ (r & 7))) * 8];
      }
#pragma unroll
      for (int j = 0; j < 4; ++j) {
        const int row = wc * 64 + j * 16 + r;
        bfr[j] = *(const bf16x8*)&Bs[(row * 8 + (cq ^ (r & 7))) * 8];
      }
#pragma unroll
      for (int i = 0; i < 4; ++i)
#pragma unroll
        for (int j = 0; j < 4; ++j)
          acc[i][j] = __builtin_amdgcn_mfma_f32_16x16x32_bf16(af[i], bfr[j], acc[i][j], 0, 0, 0);
    }
    __syncthreads();                            // all reads done before next staging
  }

  if (EPI == 2) Cf += sC * bz; else Cb += sC * bz;
#pragma unroll
  for (int i = 0; i < 4; ++i) {
#pragma unroll
    for (int j = 0; j < 4; ++j) {
      const int col = n0 + wc * 64 + j * 16 + r;      // C/D: col = lane&15
#pragma unroll
      for (int e = 0; e < 4; ++e) {
        const int rowg = m0 + wr * 64 + i * 16 + q * 4 + e;  // row = quad*4 + reg
        float v = acc[i][j][e];
        if (EPI == 0) {
          v += bias[col];
          Cb[(long)rowg * ldc + col] = f2bf(v);
        } else if (EPI == 1) {
          Cb[(long)rowg * ldc + col] = f2bf(v * scale);
        } else {
          Cf[(long)rowg * ldc + col] = v;
        }
      }
    }
  }
}

// ---------------- bf16 transpose per batch: V[S][E] (ld lda) -> Vt[E][S], 64x64 tiles ----------------
__global__ __launch_bounds__(256) void transpose_b(const unsigned short* __restrict__ V,
                                                   unsigned short* __restrict__ Vt, int lda) {
  __shared__ unsigned short tile[64][68];
  const int b = blockIdx.z;
  const unsigned short* Vb = V + (long)b * S_ * lda;
  unsigned short* Vtb = Vt + (long)b * S_ * E_;
  const int e0 = blockIdx.x * 64, j0 = blockIdx.y * 64;
  const int t = threadIdx.x;
#pragma unroll
  for (int i = 0; i < 4; ++i) {
    const int c = t + i * 256;                // 1024 ushort4 chunks
    const int row = c >> 4, c4 = c & 15;
    *(ushort4*)&tile[row][c4 * 4] = *(const ushort4*)&Vb[(long)(j0 + row) * lda + e0 + c4 * 4];
  }
  __syncthreads();
#pragma unroll
  for (int i = 0; i < 4; ++i) {
    const int c = t + i * 256;
    const int orow = c >> 4, c4 = c & 15;     // orow = e-offset, c4*4 = j-offset
    ushort4 o;
    o.x = tile[c4 * 4 + 0][orow];
    o.y = tile[c4 * 4 + 1][orow];
    o.z = tile[c4 * 4 + 2][orow];
    o.w = tile[c4 * 4 + 3][orow];
    *(ushort4*)&Vtb[(long)(e0 + orow) * S_ + j0 + c4 * 4] = o;
  }
}

// ---------------- causal softmax over bf16 scores, in-place, one wave per row ----------------
__global__ __launch_bounds__(256) void softmax_causal(unsigned short* __restrict__ Sc) {
  const int row = blockIdx.x * 4 + (threadIdx.x >> 6);   // 4 waves/block, 1 row/wave
  const int lane = threadIdx.x & 63;
  const int b = row >> 11, ii = row & (S_ - 1);
  unsigned short* prow = Sc + (long)b * S_ * S_ + (long)ii * S_;
  const int len = ii + 1;
  float v[32];
#pragma unroll
  for (int c = 0; c < 4; ++c) {
    const int base = (c * 64 + lane) * 8;
    if (base < len) {
      const uint4 u = *(const uint4*)&prow[base];
      const unsigned int w[4] = {u.x, u.y, u.z, u.w};
#pragma unroll
      for (int e = 0; e < 8; ++e) {
        const unsigned short h = (unsigned short)(w[e >> 1] >> ((e & 1) * 16));
        v[c * 8 + e] = (base + e < len) ? bf2f(h) : -3.0e38f;
      }
    } else {
#pragma unroll
      for (int e = 0; e < 8; ++e) v[c * 8 + e] = -3.0e38f;
    }
  }
  float mx = -3.0e38f;
#pragma unroll
  for (int i = 0; i < 32; ++i) mx = fmaxf(mx, v[i]);
#pragma unroll
  for (int o = 32; o; o >>= 1) mx = fmaxf(mx, __shfl_xor(mx, o));
  float sum = 0.f;
#pragma unroll
  for (int i = 0; i < 32; ++i) { v[i] = __expf(v[i] - mx); sum += v[i]; }
#pragma unroll
  for (int o = 32; o; o >>= 1) sum += __shfl_xor(sum, o);
  const float inv = 1.0f / sum;
#pragma unroll
  for (int c = 0; c < 4; ++c) {
    const int base = (c * 64 + lane) * 8;
    uint4 u;
    unsigned int w[4];
#pragma unroll
    for (int p = 0; p < 4; ++p) {
      const unsigned short lo = f2bf(v[c * 8 + p * 2] * inv);
      const unsigned short hi = f2bf(v[c * 8 + p * 2 + 1] * inv);
      w[p] = (unsigned int)lo | ((unsigned int)hi << 16);
    }
    u.x = w[0]; u.y = w[1]; u.z = w[2]; u.w = w[3];
    *(uint4*)&prow[base] = u;                  // rows always full-width: zeros beyond diagonal
  }
}

// ---------------- residual + LayerNorm ----------------
__global__ __launch_bounds__(256) void residual_ln(
    const float* __restrict__ attn, const float* __restrict__ x,
    const float* __restrict__ gamma, const float* __restrict__ beta,
    float* __restrict__ out) {
  __shared__ float rs[4], rs2[4];
  const long row = blockIdx.x;
  const int t = threadIdx.x;
  const int lane = t & 63, wave = t >> 6;
  const float4 a  = ((const float4*)(attn + row * E_))[t];
  const float4 xv = ((const float4*)(x + row * E_))[t];
  const float y0 = a.x + xv.x, y1 = a.y + xv.y, y2 = a.z + xv.z, y3 = a.w + xv.w;
  float s  = y0 + y1 + y2 + y3;
  float s2 = y0 * y0 + y1 * y1 + y2 * y2 + y3 * y3;
#pragma unroll
  for (int o = 32; o; o >>= 1) { s += __shfl_xor(s, o); s2 += __shfl_xor(s2, o); }
  if (lane == 0) { rs[wave] = s; rs2[wave] = s2; }
  __syncthreads();
  s  = rs[0] + rs[1] + rs[2] + rs[3];
  s2 = rs2[0] + rs2[1] + rs2[2] + rs2[3];
  const float mu  = s * (1.0f / E_);
  const float var = s2 * (1.0f / E_) - mu * mu;
  const float inv = rsqrtf(var + 1e-5f);
  const float4 g  = ((const float4*)gamma)[t];
  const float4 be = ((const float4*)beta)[t];
  float4 o;
  o.x = (y0 - mu) * inv * g.x + be.x;
  o.y = (y1 - mu) * inv * g.y + be.y;
  o.z = (y2 - mu) * inv * g.z + be.z;
  o.w = (y3 - mu) * inv * g.w + be.w;
  ((float4*)(out + row * E_))[t] = o;
}

extern "C" void kernel_launch(void* const* d_in, const int* in_sizes, int n_in,
                              void* d_out, int out_size, void* d_ws, size_t ws_size,
                              hipStream_t stream) {
  const float* x  = (const float*)d_in[0];
  // d_in[1] = causal mask (bool) — structurally known, not read
  const float* Wq = (const float*)d_in[2];
  const float* bq = (const float*)d_in[3];
  const float* Wk = (const float*)d_in[4];
  const float* bk = (const float*)d_in[5];
  const float* Wv = (const float*)d_in[6];
  const float* bv = (const float*)d_in[7];
  const float* gamma = (const float*)d_in[8];
  const float* beta  = (const float*)d_in[9];
  float* out = (float*)d_out;

  char* ws = (char*)d_ws;
  size_t off = 0;
  auto alloc = [&](size_t bytes) { char* p = ws + off; off += (bytes + 255) & ~(size_t)255; return p; };
  unsigned short* xb    = (unsigned short*)alloc((size_t)BS_ * E_ * 2);        // 16 MB
  unsigned short* Wqkvb = (unsigned short*)alloc((size_t)3 * E_ * E_ * 2);     // 6 MB
  float*          bqkv  = (float*)alloc((size_t)3 * E_ * 4);
  unsigned short* Cqkv  = (unsigned short*)alloc((size_t)BS_ * 3 * E_ * 2);    // 48 MB (Q|K|V, ld 3072)
  unsigned short* Vt    = (unsigned short*)alloc((size_t)BS_ * E_ * 2);        // 16 MB
  unsigned short* Sc    = (unsigned short*)alloc((size_t)B_ * S_ * S_ * 2);    // 32 MB bf16; P in-place
  float* attn = (float*)Cqkv;   // Q/K/V dead after scores GEMM + transpose

  // 1) converts: x and concatenated W/bias
  conv_f32_bf16<<<dim3(BS_ * E_ / 4 / 256), 256, 0, stream>>>(x, xb, BS_ * E_ / 4);
  conv_f32_bf16<<<dim3(E_ * E_ / 4 / 256), 256, 0, stream>>>(Wq, Wqkvb, E_ * E_ / 4);
  conv_f32_bf16<<<dim3(E_ * E_ / 4 / 256), 256, 0, stream>>>(Wk, Wqkvb + E_ * E_, E_ * E_ / 4);
  conv_f32_bf16<<<dim3(E_ * E_ / 4 / 256), 256, 0, stream>>>(Wv, Wqkvb + 2 * E_ * E_, E_ * E_ / 4);
  concat_bias<<<dim3((3 * E_ + 255) / 256), 256, 0, stream>>>(bq, bk, bv, bqkv);

  // 2) fused QKV projection: Cqkv[8192,3072] = xb · Wqkv^T + bqkv -> bf16
  dim3 g1(3 * E_ / 128, BS_ / 128, 1);
  gemm_bt<0><<<g1, 256, 0, stream>>>(xb, Wqkvb, nullptr, Cqkv, bqkv,
                                     E_, E_, E_, 3 * E_, 0, 0, 0, 1.f, 0);

  // 3) transpose V (cols 2048..3071 of Cqkv) -> Vt[E][S] per batch
  transpose_b<<<dim3(E_ / 64, S_ / 64, B_), 256, 0, stream>>>(Cqkv + 2 * E_, Vt, 3 * E_);

  // 4) scores = Q·K^T / 32 -> bf16 (causal: skip fully-masked blocks)
  dim3 g2(S_ / 128, S_ / 128, B_);
  gemm_bt<1><<<g2, 256, 0, stream>>>(Cqkv, Cqkv + E_, nullptr, Sc, nullptr,
                                     E_, 3 * E_, 3 * E_, S_,
                                     (long)S_ * 3 * E_, (long)S_ * 3 * E_, (long)S_ * S_,
                                     0.03125f, 1);

  // 5) causal softmax -> P (bf16, in-place, full rows: zeros beyond diagonal)
  softmax_causal<<<dim3(BS_ / 4), 256, 0, stream>>>(Sc);

  // 6) attn = P · V  (as P · Vt^T), K-loop clipped at diagonal
  dim3 g3(E_ / 128, S_ / 128, B_);
  gemm_bt<2><<<g3, 256, 0, stream>>>(Sc, Vt, attn, nullptr, nullptr,
                                     S_, S_, S_, E_,
                                     (long)S_ * S_, (long)S_ * E_, (long)S_ * E_, 1.f, 1);

  // 7) out = LayerNorm(attn + x) * gamma + beta
  residual_ln<<<dim3(BS_), 256, 0, stream>>>(attn, x, gamma, beta, out);
}